// Round 1
// baseline (480.127 us; speedup 1.0000x reference)
//
#include <hip/hip_runtime.h>
#include <stdint.h>

#define H_ 384
#define W_ 512
#define HW_ (H_ * W_)
#define NIMG 32
#define EPSF 1e-6f

// ---- workspace layout (bytes) ----
#define OFF_ACC    0      // 8 doubles: 0=vmcount,1=depth_sum,2=points_sum,3=ncos_sum,4=nmcount,5=pose_sum
#define OFF_MSUM   64     // 32 ints
#define OFF_FCNT   192    // 32 ints
#define OFF_KREM   320    // 32 ints
#define OFF_PREFIX 448    // 32 uints
#define OFF_SCALE  576    // 32 floats
#define OFF_HIST   704    // 32*256 uints = 32768 bytes
#define WS_BYTES   (704 + 32768)

__device__ __forceinline__ bool finitef(float x) {
    return ((__float_as_uint(x) >> 23) & 0xFFu) != 0xFFu;
}

// ---------------- radix histogram pass ----------------
__global__ __launch_bounds__(256) void hist_pass(
    const float* __restrict__ dp, const float* __restrict__ dg,
    const uint8_t* __restrict__ vmask, uint32_t* __restrict__ ws_u32,
    int shift, int first)
{
    __shared__ uint32_t lhist[256];
    __shared__ int lmsum, lfcnt;
    const int img = blockIdx.y;
    const int t = threadIdx.x;
    lhist[t] = 0;
    if (t == 0) { lmsum = 0; lfcnt = 0; }
    __syncthreads();

    const uint32_t* g_prefix = ws_u32 + OFF_PREFIX / 4;
    const uint32_t pref = first ? 0u : g_prefix[img];
    const size_t base = (size_t)img * HW_;
    const float* dpi = dp + base;
    const float* dgi = dg + base;
    const uint8_t* mi = vmask + base;

    int m2c = 0, fmc = 0;
    int curbin = -1; uint32_t rcnt = 0;

    for (int c = 0; c < 4; ++c) {
        const int pix = blockIdx.x * 4096 + c * 1024 + t * 4;
        const float4 v_dp = *reinterpret_cast<const float4*>(dpi + pix);
        const float4 v_dg = *reinterpret_cast<const float4*>(dgi + pix);
        const uchar4 v_m  = *reinterpret_cast<const uchar4*>(mi + pix);
        const float dpa[4] = {v_dp.x, v_dp.y, v_dp.z, v_dp.w};
        const float dga[4] = {v_dg.x, v_dg.y, v_dg.z, v_dg.w};
        const uint8_t ma[4] = {v_m.x, v_m.y, v_m.z, v_m.w};
#pragma unroll
        for (int e = 0; e < 4; ++e) {
            const float dgv = dga[e], dpv = dpa[e];
            const bool vm = ma[e] && finitef(dgv) && (dgv > 1e-6f);
            const bool m2 = vm && finitef(dpv) && (dpv > EPSF);
            const float ratio = dpv / fmaxf(dgv, EPSF);
            const bool fm = m2 && finitef(ratio);
            m2c += (int)m2; fmc += (int)fm;
            if (fm) {
                const uint32_t key = __float_as_uint(ratio);
                bool match = true;
                if (!first) match = (key >> (shift + 8)) == (pref >> (shift + 8));
                if (match) {
                    const int bin = (int)((key >> shift) & 0xFFu);
                    if (bin == curbin) { rcnt++; }
                    else {
                        if (curbin >= 0) atomicAdd(&lhist[curbin], rcnt);
                        curbin = bin; rcnt = 1;
                    }
                }
            }
        }
    }
    if (curbin >= 0) atomicAdd(&lhist[curbin], rcnt);

    if (first) {
        for (int o = 32; o > 0; o >>= 1) { m2c += __shfl_down(m2c, o); fmc += __shfl_down(fmc, o); }
        if ((t & 63) == 0) { atomicAdd(&lmsum, m2c); atomicAdd(&lfcnt, fmc); }
    }
    __syncthreads();

    uint32_t* g_hist = ws_u32 + OFF_HIST / 4 + img * 256;
    if (lhist[t]) atomicAdd(&g_hist[t], lhist[t]);
    if (first && t == 0) {
        int* g_msum = (int*)(ws_u32 + OFF_MSUM / 4);
        int* g_fcnt = (int*)(ws_u32 + OFF_FCNT / 4);
        atomicAdd(&g_msum[img], lmsum);
        atomicAdd(&g_fcnt[img], lfcnt);
    }
}

// ---------------- radix select (+ pose loss on final pass) ----------------
__global__ __launch_bounds__(256) void select_pass(
    uint32_t* __restrict__ ws_u32, int shift,
    const float* __restrict__ intr, const float* __restrict__ posegt,
    const float* __restrict__ posepred)
{
    const int img = blockIdx.x;
    const int t = threadIdx.x;
    uint32_t* g_hist = ws_u32 + OFF_HIST / 4 + img * 256;
    __shared__ uint32_t h[256];
    h[t] = g_hist[t];
    __syncthreads();

    if (t == 0) {
        int* g_msum = (int*)(ws_u32 + OFF_MSUM / 4);
        int* g_fcnt = (int*)(ws_u32 + OFF_FCNT / 4);
        int* g_krem = (int*)(ws_u32 + OFF_KREM / 4);
        uint32_t* g_prefix = ws_u32 + OFF_PREFIX / 4;
        const int fcnt = g_fcnt[img];
        int k = (shift == 24) ? max((fcnt - 1) / 2, 0) : g_krem[img];
        uint32_t cum = 0; int bin = 0;
        for (int v = 0; v < 256; ++v) {
            const uint32_t c = h[v];
            if (cum + c > (uint32_t)k) { bin = v; break; }
            cum += c;
        }
        g_krem[img] = k - (int)cum;
        const uint32_t pref = g_prefix[img] | ((uint32_t)bin << shift);
        g_prefix[img] = pref;

        if (shift == 0) {
            const float med = __uint_as_float(pref);
            float sc = fminf(fmaxf(med, 0.001f), 1000.0f);
            const int msum = g_msum[img];
            if (msum < 16 || fcnt == 0) sc = 1.0f;
            ((float*)(ws_u32 + OFF_SCALE / 4))[img] = sc;

            // ---- pose encoding + smooth L1 for this image ----
            const float* p = posegt + img * 16;
            const float m00 = p[0], m01 = p[1], m02 = p[2], tx = p[3];
            const float m10 = p[4], m11 = p[5], m12 = p[6], ty = p[7];
            const float m20 = p[8], m21 = p[9], m22 = p[10], tz = p[11];
            float qa[4];
            qa[0] = sqrtf(fmaxf(1.0f + m00 + m11 + m22, 0.0f));
            qa[1] = sqrtf(fmaxf(1.0f + m00 - m11 - m22, 0.0f));
            qa[2] = sqrtf(fmaxf(1.0f - m00 + m11 - m22, 0.0f));
            qa[3] = sqrtf(fmaxf(1.0f - m00 - m11 + m22, 0.0f));
            int best = 0; float bv = qa[0];
            for (int i2 = 1; i2 < 4; ++i2) if (qa[i2] > bv) { bv = qa[i2]; best = i2; }
            float c0, c1, c2, c3;
            if (best == 0)      { c0 = qa[0]*qa[0]; c1 = m21 - m12;   c2 = m02 - m20;   c3 = m10 - m01; }
            else if (best == 1) { c0 = m21 - m12;   c1 = qa[1]*qa[1]; c2 = m10 + m01;   c3 = m02 + m20; }
            else if (best == 2) { c0 = m02 - m20;   c1 = m10 + m01;   c2 = qa[2]*qa[2]; c3 = m12 + m21; }
            else                { c0 = m10 - m01;   c1 = m20 + m02;   c2 = m21 + m12;   c3 = qa[3]*qa[3]; }
            const float denom = 2.0f * fmaxf(qa[best], 0.1f);
            float q0 = c0 / denom, q1 = c1 / denom, q2 = c2 / denom, q3 = c3 / denom;
            if (q0 < 0.0f) { q0 = -q0; q1 = -q1; q2 = -q2; q3 = -q3; }
            const float fx = intr[img * 9 + 0], fy = intr[img * 9 + 4];
            const float fovh = 2.0f * atanf((H_ * 0.5f) / fy);
            const float fovw = 2.0f * atanf((W_ * 0.5f) / fx);
            const float pg[9] = {tx * sc, ty * sc, tz * sc, q0, q1, q2, q3, fovh, fovw};
            const float* ppred = posepred + img * 9;
            float s = 0.0f;
            for (int i2 = 0; i2 < 9; ++i2) {
                const float d = fabsf(ppred[i2] - pg[i2]);
                s += (d < 1.0f) ? 0.5f * d * d : d - 0.5f;
            }
            double* acc = (double*)(ws_u32 + OFF_ACC / 4);
            atomicAdd(&acc[5], (double)s);
        }
    }
    __syncthreads();
    g_hist[t] = 0;   // reset for next pass
}

// ---------------- fused main loss pass ----------------
__global__ __launch_bounds__(256) void main_loss(
    const float* __restrict__ dp, const float* __restrict__ dg,
    const uint8_t* __restrict__ vmask, const float* __restrict__ pts_pred,
    const float* __restrict__ intr, const float* __restrict__ posegt,
    uint32_t* __restrict__ ws_u32)
{
    const int img = blockIdx.y;
    const int t = threadIdx.x;
    __shared__ float sP[17]; // R[9], T[3], fx, fy, cx, cy, scale
    if (t == 0) {
        const float* p = posegt + img * 16;
        sP[0] = p[0]; sP[1] = p[1]; sP[2] = p[2];  sP[9]  = p[3];
        sP[3] = p[4]; sP[4] = p[5]; sP[5] = p[6];  sP[10] = p[7];
        sP[6] = p[8]; sP[7] = p[9]; sP[8] = p[10]; sP[11] = p[11];
        sP[12] = intr[img * 9 + 0]; sP[13] = intr[img * 9 + 4];
        sP[14] = intr[img * 9 + 2]; sP[15] = intr[img * 9 + 5];
        sP[16] = ((const float*)(ws_u32 + OFF_SCALE / 4))[img];
    }
    __syncthreads();
    const float R00 = sP[0], R01 = sP[1], R02 = sP[2];
    const float R10 = sP[3], R11 = sP[4], R12 = sP[5];
    const float R20 = sP[6], R21 = sP[7], R22 = sP[8];
    const float T0 = sP[9], T1 = sP[10], T2 = sP[11];
    const float inv_fx = 1.0f / fmaxf(sP[12], EPSF);
    const float inv_fy = 1.0f / fmaxf(sP[13], EPSF);
    const float cx = sP[14], cy = sP[15];
    const float sc = sP[16];

    const size_t base = (size_t)img * HW_;
    const int pix0 = (blockIdx.x * 256 + t) * 4;
    const int i = pix0 >> 9;
    const int j0 = pix0 & 511;

    const float4 v_dp = *reinterpret_cast<const float4*>(dp + base + pix0);
    const float4 v_dg = *reinterpret_cast<const float4*>(dg + base + pix0);
    const uchar4 v_m  = *reinterpret_cast<const uchar4*>(vmask + base + pix0);
    const float4 ppA = *reinterpret_cast<const float4*>(pts_pred + (base + pix0) * 3);
    const float4 ppB = *reinterpret_cast<const float4*>(pts_pred + (base + pix0) * 3 + 4);
    const float4 ppC = *reinterpret_cast<const float4*>(pts_pred + (base + pix0) * 3 + 8);
    const float ppv[12] = {ppA.x, ppA.y, ppA.z, ppA.w, ppB.x, ppB.y, ppB.z, ppB.w,
                           ppC.x, ppC.y, ppC.z, ppC.w};
    const float dpa[4] = {v_dp.x, v_dp.y, v_dp.z, v_dp.w};
    const float dga[4] = {v_dg.x, v_dg.y, v_dg.z, v_dg.w};
    const uint8_t ma[4] = {v_m.x, v_m.y, v_m.z, v_m.w};

    const float ay   = ((float)i - cy) * inv_fy;
    const float ay_m = ((float)(i - 1) - cy) * inv_fy;
    const float ay_p = ((float)(i + 1) - cy) * inv_fy;
    const bool row_int = (i >= 1) && (i <= H_ - 2);

    float dsum = 0.0f, psum = 0.0f, nsum = 0.0f;
    int vcnt = 0, ncnt = 0;

#pragma unroll
    for (int e = 0; e < 4; ++e) {
        const int j = j0 + e;
        const float dgv = dga[e], dpv = dpa[e];
        const bool vm = ma[e] && finitef(dgv) && (dgv > 1e-6f);
        if (!vm) continue;
        vcnt++;
        const float dal = dgv * sc;
        dsum += fabsf(dpv - dal);
        const float ax = ((float)j - cx) * inv_fx;
        const float cxx = ax * dal, cyy = ay * dal, czz = dal;
        const float wx = R00 * cxx + R01 * cyy + R02 * czz + T0;
        const float wy = R10 * cxx + R11 * cyy + R12 * czz + T1;
        const float wz = R20 * cxx + R21 * cyy + R22 * czz + T2;
        psum += fabsf(ppv[3 * e] - wx) + fabsf(ppv[3 * e + 1] - wy) + fabsf(ppv[3 * e + 2] - wz);

        if (row_int && j >= 1 && j <= W_ - 2) {
            ncnt++;
            const int pc = i * W_ + j;
            const float pdL = dp[base + pc - 1],  pdR = dp[base + pc + 1];
            const float pdU = dp[base + pc - W_], pdD = dp[base + pc + W_];
            const float gdL = dg[base + pc - 1],  gdR = dg[base + pc + 1];
            const float gdU = dg[base + pc - W_], gdD = dg[base + pc + W_];
            const float ax_m = ((float)(j - 1) - cx) * inv_fx;
            const float ax_p = ((float)(j + 1) - cx) * inv_fx;

            float npx, npy, npz, ngx, ngy, ngz;
            {
                const float fxx = ax_p * pdR - ax_m * pdL;
                const float fxy = ay * (pdR - pdL);
                const float fxz = pdR - pdL;
                const float fyx = ax * (pdD - pdU);
                const float fyy = ay_p * pdD - ay_m * pdU;
                const float fyz = pdD - pdU;
                float cxp = fyy * fxz - fyz * fxy;
                float cyp = fyz * fxx - fyx * fxz;
                float czp = fyx * fxy - fyy * fxx;
                float nrm = sqrtf(cxp * cxp + cyp * cyp + czp * czp);
                float inv = 1.0f / fmaxf(nrm, EPSF);
                cxp *= inv; cyp *= inv; czp *= inv;
                nrm = sqrtf(cxp * cxp + cyp * cyp + czp * czp);
                inv = 1.0f / fmaxf(nrm, EPSF);
                npx = cxp * inv; npy = cyp * inv; npz = czp * inv;
            }
            {
                const float fxx = ax_p * gdR - ax_m * gdL;
                const float fxy = ay * (gdR - gdL);
                const float fxz = gdR - gdL;
                const float fyx = ax * (gdD - gdU);
                const float fyy = ay_p * gdD - ay_m * gdU;
                const float fyz = gdD - gdU;
                float cxp = fyy * fxz - fyz * fxy;
                float cyp = fyz * fxx - fyx * fxz;
                float czp = fyx * fxy - fyy * fxx;
                float nrm = sqrtf(cxp * cxp + cyp * cyp + czp * czp);
                float inv = 1.0f / fmaxf(nrm, EPSF);
                cxp *= inv; cyp *= inv; czp *= inv;
                nrm = sqrtf(cxp * cxp + cyp * cyp + czp * czp);
                inv = 1.0f / fmaxf(nrm, EPSF);
                ngx = cxp * inv; ngy = cyp * inv; ngz = czp * inv;
            }
            float cosv = npx * ngx + npy * ngy + npz * ngz;
            cosv = fminf(fmaxf(cosv, -1.0f), 1.0f);
            nsum += 1.0f - cosv;
        }
    }

    // block reduction -> double atomics
    float vals[5] = {(float)vcnt, dsum, psum, nsum, (float)ncnt};
    __shared__ float red[4][5];
    const int wave = t >> 6, lane = t & 63;
#pragma unroll
    for (int q = 0; q < 5; ++q) {
        float v = vals[q];
        for (int o = 32; o > 0; o >>= 1) v += __shfl_down(v, o);
        if (lane == 0) red[wave][q] = v;
    }
    __syncthreads();
    if (t == 0) {
        double* acc = (double*)(ws_u32 + OFF_ACC / 4);
#pragma unroll
        for (int q = 0; q < 5; ++q) {
            const float s = red[0][q] + red[1][q] + red[2][q] + red[3][q];
            atomicAdd(&acc[q == 0 ? 0 : q], (double)s);
        }
    }
}

// ---------------- finalize ----------------
__global__ void finalize_k(const uint32_t* __restrict__ ws_u32, float* __restrict__ out)
{
    const double* acc = (const double*)(ws_u32 + OFF_ACC / 4);
    const double vmc = acc[0];
    const double depth_loss  = acc[1] / fmax(vmc, 1.0);
    const double points_loss = acc[2] / fmax(3.0 * vmc, 1.0);
    const double normal_loss = acc[3] / fmax(acc[4], 1.0);
    const double pose_loss   = acc[5] / 288.0;
    out[0] = (float)(pose_loss + depth_loss + points_loss + 0.1 * normal_loss);
}

extern "C" void kernel_launch(void* const* d_in, const int* in_sizes, int n_in,
                              void* d_out, int out_size, void* d_ws, size_t ws_size,
                              hipStream_t stream)
{
    const float*   dp       = (const float*)d_in[0];   // depth_pred  (4,8,384,512)
    const float*   pts_pred = (const float*)d_in[1];   // points_pred (4,8,384,512,3)
    const float*   posepred = (const float*)d_in[2];   // pose_pred   (4,8,9)
    const float*   dg       = (const float*)d_in[3];   // depth_gt    (4,8,384,512)
    const float*   intr     = (const float*)d_in[4];   // intrinsics  (4,8,3,3)
    const float*   posegt   = (const float*)d_in[5];   // pose_matrix_gt (4,8,4,4)
    const uint8_t* vmask    = (const uint8_t*)d_in[6]; // valid_mask  (4,8,384,512) bool
    float* out = (float*)d_out;
    uint32_t* ws = (uint32_t*)d_ws;

    hipMemsetAsync(d_ws, 0, WS_BYTES, stream);

    const dim3 hgrid(48, NIMG);
    hist_pass<<<hgrid, 256, 0, stream>>>(dp, dg, vmask, ws, 24, 1);
    select_pass<<<NIMG, 256, 0, stream>>>(ws, 24, intr, posegt, posepred);
    hist_pass<<<hgrid, 256, 0, stream>>>(dp, dg, vmask, ws, 16, 0);
    select_pass<<<NIMG, 256, 0, stream>>>(ws, 16, intr, posegt, posepred);
    hist_pass<<<hgrid, 256, 0, stream>>>(dp, dg, vmask, ws, 8, 0);
    select_pass<<<NIMG, 256, 0, stream>>>(ws, 8, intr, posegt, posepred);
    hist_pass<<<hgrid, 256, 0, stream>>>(dp, dg, vmask, ws, 0, 0);
    select_pass<<<NIMG, 256, 0, stream>>>(ws, 0, intr, posegt, posepred);

    main_loss<<<dim3(192, NIMG), 256, 0, stream>>>(dp, dg, vmask, pts_pred, intr, posegt, ws);
    finalize_k<<<1, 1, 0, stream>>>(ws, out);
}

// Round 2
// 147.049 us; speedup vs baseline: 3.2651x; 3.2651x over previous
//
#include <hip/hip_runtime.h>
#include <stdint.h>

#define H_ 384
#define W_ 512
#define HW_ (H_ * W_)
#define NIMG 32
#define EPSF 1e-6f
#define NPARTS (192 * 32)

// ---- workspace layout (bytes) ----
#define OFF_ACC    0      // 8 doubles: [5]=pose_sum (others unused now)
#define OFF_MSUM   64     // 32 ints
#define OFF_FCNT   192    // 32 ints
#define OFF_KREM   320    // 32 ints
#define OFF_PREFIX 448    // 32 uints
#define OFF_SCALE  576    // 32 floats
#define OFF_HIST   704    // 32*256 uints = 32768 bytes
#define OFF_PART   33472  // NPARTS*5 floats = 122880 bytes (not memset; fully overwritten)
#define WS_ZERO_BYTES 33472

__device__ __forceinline__ bool finitef(float x) {
    return ((__float_as_uint(x) >> 23) & 0xFFu) != 0xFFu;
}

// ---------------- radix histogram pass ----------------
__global__ __launch_bounds__(256) void hist_pass(
    const float* __restrict__ dp, const float* __restrict__ dg,
    const uint8_t* __restrict__ vmask, uint32_t* __restrict__ ws_u32,
    int shift, int first)
{
    __shared__ uint32_t lhist[256];
    __shared__ int lmsum, lfcnt;
    const int img = blockIdx.y;
    const int t = threadIdx.x;
    lhist[t] = 0;
    if (t == 0) { lmsum = 0; lfcnt = 0; }
    __syncthreads();

    const uint32_t* g_prefix = ws_u32 + OFF_PREFIX / 4;
    const uint32_t pref = first ? 0u : g_prefix[img];
    const size_t base = (size_t)img * HW_;
    const float* dpi = dp + base;
    const float* dgi = dg + base;
    const uint8_t* mi = vmask + base;

    int m2c = 0, fmc = 0;
    int curbin = -1; uint32_t rcnt = 0;

    for (int c = 0; c < 4; ++c) {
        const int pix = blockIdx.x * 4096 + c * 1024 + t * 4;
        const float4 v_dp = *reinterpret_cast<const float4*>(dpi + pix);
        const float4 v_dg = *reinterpret_cast<const float4*>(dgi + pix);
        const uchar4 v_m  = *reinterpret_cast<const uchar4*>(mi + pix);
        const float dpa[4] = {v_dp.x, v_dp.y, v_dp.z, v_dp.w};
        const float dga[4] = {v_dg.x, v_dg.y, v_dg.z, v_dg.w};
        const uint8_t ma[4] = {v_m.x, v_m.y, v_m.z, v_m.w};
#pragma unroll
        for (int e = 0; e < 4; ++e) {
            const float dgv = dga[e], dpv = dpa[e];
            const bool vm = ma[e] && finitef(dgv) && (dgv > 1e-6f);
            const bool m2 = vm && finitef(dpv) && (dpv > EPSF);
            const float ratio = dpv / fmaxf(dgv, EPSF);
            const bool fm = m2 && finitef(ratio);
            m2c += (int)m2; fmc += (int)fm;
            if (fm) {
                const uint32_t key = __float_as_uint(ratio);
                bool match = true;
                if (!first) match = (key >> (shift + 8)) == (pref >> (shift + 8));
                if (match) {
                    const int bin = (int)((key >> shift) & 0xFFu);
                    if (bin == curbin) { rcnt++; }
                    else {
                        if (curbin >= 0) atomicAdd(&lhist[curbin], rcnt);
                        curbin = bin; rcnt = 1;
                    }
                }
            }
        }
    }
    if (curbin >= 0) atomicAdd(&lhist[curbin], rcnt);

    if (first) {
        for (int o = 32; o > 0; o >>= 1) { m2c += __shfl_down(m2c, o); fmc += __shfl_down(fmc, o); }
        if ((t & 63) == 0) { atomicAdd(&lmsum, m2c); atomicAdd(&lfcnt, fmc); }
    }
    __syncthreads();

    uint32_t* g_hist = ws_u32 + OFF_HIST / 4 + img * 256;
    if (lhist[t]) atomicAdd(&g_hist[t], lhist[t]);
    if (first && t == 0) {
        int* g_msum = (int*)(ws_u32 + OFF_MSUM / 4);
        int* g_fcnt = (int*)(ws_u32 + OFF_FCNT / 4);
        atomicAdd(&g_msum[img], lmsum);
        atomicAdd(&g_fcnt[img], lfcnt);
    }
}

// ---------------- radix select (+ pose loss on final pass) ----------------
__global__ __launch_bounds__(256) void select_pass(
    uint32_t* __restrict__ ws_u32, int shift,
    const float* __restrict__ intr, const float* __restrict__ posegt,
    const float* __restrict__ posepred)
{
    const int img = blockIdx.x;
    const int t = threadIdx.x;
    uint32_t* g_hist = ws_u32 + OFF_HIST / 4 + img * 256;
    __shared__ uint32_t h[256];
    h[t] = g_hist[t];
    __syncthreads();

    if (t == 0) {
        int* g_msum = (int*)(ws_u32 + OFF_MSUM / 4);
        int* g_fcnt = (int*)(ws_u32 + OFF_FCNT / 4);
        int* g_krem = (int*)(ws_u32 + OFF_KREM / 4);
        uint32_t* g_prefix = ws_u32 + OFF_PREFIX / 4;
        const int fcnt = g_fcnt[img];
        int k = (shift == 24) ? max((fcnt - 1) / 2, 0) : g_krem[img];
        uint32_t cum = 0; int bin = 0;
        for (int v = 0; v < 256; ++v) {
            const uint32_t c = h[v];
            if (cum + c > (uint32_t)k) { bin = v; break; }
            cum += c;
        }
        g_krem[img] = k - (int)cum;
        const uint32_t pref = g_prefix[img] | ((uint32_t)bin << shift);
        g_prefix[img] = pref;

        if (shift == 0) {
            const float med = __uint_as_float(pref);
            float sc = fminf(fmaxf(med, 0.001f), 1000.0f);
            const int msum = g_msum[img];
            if (msum < 16 || fcnt == 0) sc = 1.0f;
            ((float*)(ws_u32 + OFF_SCALE / 4))[img] = sc;

            // ---- pose encoding + smooth L1 for this image ----
            const float* p = posegt + img * 16;
            const float m00 = p[0], m01 = p[1], m02 = p[2], tx = p[3];
            const float m10 = p[4], m11 = p[5], m12 = p[6], ty = p[7];
            const float m20 = p[8], m21 = p[9], m22 = p[10], tz = p[11];
            float qa[4];
            qa[0] = sqrtf(fmaxf(1.0f + m00 + m11 + m22, 0.0f));
            qa[1] = sqrtf(fmaxf(1.0f + m00 - m11 - m22, 0.0f));
            qa[2] = sqrtf(fmaxf(1.0f - m00 + m11 - m22, 0.0f));
            qa[3] = sqrtf(fmaxf(1.0f - m00 - m11 + m22, 0.0f));
            int best = 0; float bv = qa[0];
            for (int i2 = 1; i2 < 4; ++i2) if (qa[i2] > bv) { bv = qa[i2]; best = i2; }
            float c0, c1, c2, c3;
            if (best == 0)      { c0 = qa[0]*qa[0]; c1 = m21 - m12;   c2 = m02 - m20;   c3 = m10 - m01; }
            else if (best == 1) { c0 = m21 - m12;   c1 = qa[1]*qa[1]; c2 = m10 + m01;   c3 = m02 + m20; }
            else if (best == 2) { c0 = m02 - m20;   c1 = m10 + m01;   c2 = qa[2]*qa[2]; c3 = m12 + m21; }
            else                { c0 = m10 - m01;   c1 = m20 + m02;   c2 = m21 + m12;   c3 = qa[3]*qa[3]; }
            const float denom = 2.0f * fmaxf(qa[best], 0.1f);
            float q0 = c0 / denom, q1 = c1 / denom, q2 = c2 / denom, q3 = c3 / denom;
            if (q0 < 0.0f) { q0 = -q0; q1 = -q1; q2 = -q2; q3 = -q3; }
            const float fx = intr[img * 9 + 0], fy = intr[img * 9 + 4];
            const float fovh = 2.0f * atanf((H_ * 0.5f) / fy);
            const float fovw = 2.0f * atanf((W_ * 0.5f) / fx);
            const float pg[9] = {tx * sc, ty * sc, tz * sc, q0, q1, q2, q3, fovh, fovw};
            const float* ppred = posepred + img * 9;
            float s = 0.0f;
            for (int i2 = 0; i2 < 9; ++i2) {
                const float d = fabsf(ppred[i2] - pg[i2]);
                s += (d < 1.0f) ? 0.5f * d * d : d - 0.5f;
            }
            double* acc = (double*)(ws_u32 + OFF_ACC / 4);
            atomicAdd(&acc[5], (double)s);
        }
    }
    __syncthreads();
    g_hist[t] = 0;   // reset for next pass
}

// ---------------- fused main loss pass (no atomics, no divergence) ----------------
__global__ __launch_bounds__(256) void main_loss(
    const float* __restrict__ dp, const float* __restrict__ dg,
    const uint8_t* __restrict__ vmask, const float* __restrict__ pts_pred,
    const float* __restrict__ intr, const float* __restrict__ posegt,
    uint32_t* __restrict__ ws_u32)
{
    const int img = blockIdx.y;
    const int t = threadIdx.x;
    __shared__ float sP[17]; // R[9], T[3], fx, fy, cx, cy, scale
    if (t == 0) {
        const float* p = posegt + img * 16;
        sP[0] = p[0]; sP[1] = p[1]; sP[2] = p[2];  sP[9]  = p[3];
        sP[3] = p[4]; sP[4] = p[5]; sP[5] = p[6];  sP[10] = p[7];
        sP[6] = p[8]; sP[7] = p[9]; sP[8] = p[10]; sP[11] = p[11];
        sP[12] = intr[img * 9 + 0]; sP[13] = intr[img * 9 + 4];
        sP[14] = intr[img * 9 + 2]; sP[15] = intr[img * 9 + 5];
        sP[16] = ((const float*)(ws_u32 + OFF_SCALE / 4))[img];
    }
    __syncthreads();
    const float R00 = sP[0], R01 = sP[1], R02 = sP[2];
    const float R10 = sP[3], R11 = sP[4], R12 = sP[5];
    const float R20 = sP[6], R21 = sP[7], R22 = sP[8];
    const float T0 = sP[9], T1 = sP[10], T2 = sP[11];
    const float inv_fx = 1.0f / fmaxf(sP[12], EPSF);
    const float inv_fy = 1.0f / fmaxf(sP[13], EPSF);
    const float cx = sP[14], cy = sP[15];
    const float sc = sP[16];

    const size_t base = (size_t)img * HW_;
    const int pix0 = (blockIdx.x * 256 + t) * 4;
    const int i = pix0 >> 9;
    const int j0 = pix0 & 511;
    const float* dpi = dp + base;
    const float* dgi = dg + base;

    // ---- issue ALL loads up front, unconditional, clamped ----
    const float4 v_dp = *reinterpret_cast<const float4*>(dpi + pix0);
    const float4 v_dg = *reinterpret_cast<const float4*>(dgi + pix0);
    const uchar4 v_m  = *reinterpret_cast<const uchar4*>(vmask + base + pix0);
    const float4 ppA = *reinterpret_cast<const float4*>(pts_pred + (base + pix0) * 3);
    const float4 ppB = *reinterpret_cast<const float4*>(pts_pred + (base + pix0) * 3 + 4);
    const float4 ppC = *reinterpret_cast<const float4*>(pts_pred + (base + pix0) * 3 + 8);

    const int im = (i > 0) ? i - 1 : 0;
    const int ip = (i < H_ - 1) ? i + 1 : i;
    const int jme = (j0 > 0) ? j0 - 1 : 0;
    const int jpe = (j0 + 4 < W_) ? j0 + 4 : W_ - 1;
    const float4 dpU = *reinterpret_cast<const float4*>(dpi + im * W_ + j0);
    const float4 dpD = *reinterpret_cast<const float4*>(dpi + ip * W_ + j0);
    const float4 dgU = *reinterpret_cast<const float4*>(dgi + im * W_ + j0);
    const float4 dgD = *reinterpret_cast<const float4*>(dgi + ip * W_ + j0);
    const float dpLe = dpi[i * W_ + jme], dpRe = dpi[i * W_ + jpe];
    const float dgLe = dgi[i * W_ + jme], dgRe = dgi[i * W_ + jpe];

    const float ppv[12] = {ppA.x, ppA.y, ppA.z, ppA.w, ppB.x, ppB.y, ppB.z, ppB.w,
                           ppC.x, ppC.y, ppC.z, ppC.w};
    const float dpa[4] = {v_dp.x, v_dp.y, v_dp.z, v_dp.w};
    const float dga[4] = {v_dg.x, v_dg.y, v_dg.z, v_dg.w};
    const float dpUa[4] = {dpU.x, dpU.y, dpU.z, dpU.w};
    const float dpDa[4] = {dpD.x, dpD.y, dpD.z, dpD.w};
    const float dgUa[4] = {dgU.x, dgU.y, dgU.z, dgU.w};
    const float dgDa[4] = {dgD.x, dgD.y, dgD.z, dgD.w};
    const uint8_t ma[4] = {v_m.x, v_m.y, v_m.z, v_m.w};

    const float ay   = ((float)i - cy) * inv_fy;
    const float ay_m = ((float)(i - 1) - cy) * inv_fy;
    const float ay_p = ((float)(i + 1) - cy) * inv_fy;
    const bool row_int = (i >= 1) && (i <= H_ - 2);

    float dsum = 0.0f, psum = 0.0f, nsum = 0.0f;
    float vcnt = 0.0f, ncnt = 0.0f;

#pragma unroll
    for (int e = 0; e < 4; ++e) {
        const int j = j0 + e;
        const float dgv = dga[e], dpv = dpa[e];
        const bool vm = ma[e] && finitef(dgv) && (dgv > 1e-6f);
        const bool nm = vm && row_int && (j >= 1) && (j <= W_ - 2);
        vcnt += vm ? 1.0f : 0.0f;
        ncnt += nm ? 1.0f : 0.0f;

        const float dal = dgv * sc;
        dsum += vm ? fabsf(dpv - dal) : 0.0f;
        const float ax = ((float)j - cx) * inv_fx;
        const float cxx = ax * dal, cyy = ay * dal, czz = dal;
        const float wx = R00 * cxx + R01 * cyy + R02 * czz + T0;
        const float wy = R10 * cxx + R11 * cyy + R12 * czz + T1;
        const float wz = R20 * cxx + R21 * cyy + R22 * czz + T2;
        const float pl = fabsf(ppv[3 * e] - wx) + fabsf(ppv[3 * e + 1] - wy)
                       + fabsf(ppv[3 * e + 2] - wz);
        psum += vm ? pl : 0.0f;

        // normals (unconditional compute, masked accumulate)
        const float pdL = (e == 0) ? dpLe : dpa[e - 1];
        const float pdR = (e == 3) ? dpRe : dpa[e + 1];
        const float gdL = (e == 0) ? dgLe : dga[e - 1];
        const float gdR = (e == 3) ? dgRe : dga[e + 1];
        const float pdU = dpUa[e], pdD = dpDa[e];
        const float gdU = dgUa[e], gdD = dgDa[e];
        const float ax_m = ((float)(j - 1) - cx) * inv_fx;
        const float ax_p = ((float)(j + 1) - cx) * inv_fx;

        float npx, npy, npz, ngx, ngy, ngz;
        {
            const float fxx = ax_p * pdR - ax_m * pdL;
            const float fxy = ay * (pdR - pdL);
            const float fxz = pdR - pdL;
            const float fyx = ax * (pdD - pdU);
            const float fyy = ay_p * pdD - ay_m * pdU;
            const float fyz = pdD - pdU;
            float cxp = fyy * fxz - fyz * fxy;
            float cyp = fyz * fxx - fyx * fxz;
            float czp = fyx * fxy - fyy * fxx;
            float nrm = sqrtf(cxp * cxp + cyp * cyp + czp * czp);
            float inv = 1.0f / fmaxf(nrm, EPSF);
            cxp *= inv; cyp *= inv; czp *= inv;
            nrm = sqrtf(cxp * cxp + cyp * cyp + czp * czp);
            inv = 1.0f / fmaxf(nrm, EPSF);
            npx = cxp * inv; npy = cyp * inv; npz = czp * inv;
        }
        {
            const float fxx = ax_p * gdR - ax_m * gdL;
            const float fxy = ay * (gdR - gdL);
            const float fxz = gdR - gdL;
            const float fyx = ax * (gdD - gdU);
            const float fyy = ay_p * gdD - ay_m * gdU;
            const float fyz = gdD - gdU;
            float cxp = fyy * fxz - fyz * fxy;
            float cyp = fyz * fxx - fyx * fxz;
            float czp = fyx * fxy - fyy * fxx;
            float nrm = sqrtf(cxp * cxp + cyp * cyp + czp * czp);
            float inv = 1.0f / fmaxf(nrm, EPSF);
            cxp *= inv; cyp *= inv; czp *= inv;
            nrm = sqrtf(cxp * cxp + cyp * cyp + czp * czp);
            inv = 1.0f / fmaxf(nrm, EPSF);
            ngx = cxp * inv; ngy = cyp * inv; ngz = czp * inv;
        }
        float cosv = npx * ngx + npy * ngy + npz * ngz;
        cosv = fminf(fmaxf(cosv, -1.0f), 1.0f);
        nsum += nm ? (1.0f - cosv) : 0.0f;
    }

    // block reduction -> per-block partial write (NO global atomics)
    float vals[5] = {vcnt, dsum, psum, nsum, ncnt};
    __shared__ float red[4][5];
    const int wave = t >> 6, lane = t & 63;
#pragma unroll
    for (int q = 0; q < 5; ++q) {
        float v = vals[q];
        for (int o = 32; o > 0; o >>= 1) v += __shfl_down(v, o);
        if (lane == 0) red[wave][q] = v;
    }
    __syncthreads();
    if (t == 0) {
        const int slot = blockIdx.y * gridDim.x + blockIdx.x;
        float* part = (float*)(ws_u32 + OFF_PART / 4) + slot * 5;
#pragma unroll
        for (int q = 0; q < 5; ++q)
            part[q] = red[0][q] + red[1][q] + red[2][q] + red[3][q];
    }
}

// ---------------- finalize: reduce partials ----------------
__global__ __launch_bounds__(256) void finalize_k(const uint32_t* __restrict__ ws_u32,
                                                  float* __restrict__ out)
{
    const float* part = (const float*)(ws_u32 + OFF_PART / 4);
    const int t = threadIdx.x;
    double s[5] = {0, 0, 0, 0, 0};
    for (int slot = t; slot < NPARTS; slot += 256) {
#pragma unroll
        for (int q = 0; q < 5; ++q) s[q] += (double)part[slot * 5 + q];
    }
    __shared__ double red[4][5];
    const int wave = t >> 6, lane = t & 63;
#pragma unroll
    for (int q = 0; q < 5; ++q) {
        double v = s[q];
        for (int o = 32; o > 0; o >>= 1) v += __shfl_down(v, o);
        if (lane == 0) red[wave][q] = v;
    }
    __syncthreads();
    if (t == 0) {
        double tot[5];
#pragma unroll
        for (int q = 0; q < 5; ++q)
            tot[q] = red[0][q] + red[1][q] + red[2][q] + red[3][q];
        const double* acc = (const double*)(ws_u32 + OFF_ACC / 4);
        const double vmc = tot[0];
        const double depth_loss  = tot[1] / fmax(vmc, 1.0);
        const double points_loss = tot[2] / fmax(3.0 * vmc, 1.0);
        const double normal_loss = tot[3] / fmax(tot[4], 1.0);
        const double pose_loss   = acc[5] / 288.0;
        out[0] = (float)(pose_loss + depth_loss + points_loss + 0.1 * normal_loss);
    }
}

extern "C" void kernel_launch(void* const* d_in, const int* in_sizes, int n_in,
                              void* d_out, int out_size, void* d_ws, size_t ws_size,
                              hipStream_t stream)
{
    const float*   dp       = (const float*)d_in[0];   // depth_pred  (4,8,384,512)
    const float*   pts_pred = (const float*)d_in[1];   // points_pred (4,8,384,512,3)
    const float*   posepred = (const float*)d_in[2];   // pose_pred   (4,8,9)
    const float*   dg       = (const float*)d_in[3];   // depth_gt    (4,8,384,512)
    const float*   intr     = (const float*)d_in[4];   // intrinsics  (4,8,3,3)
    const float*   posegt   = (const float*)d_in[5];   // pose_matrix_gt (4,8,4,4)
    const uint8_t* vmask    = (const uint8_t*)d_in[6]; // valid_mask  (4,8,384,512) bool
    float* out = (float*)d_out;
    uint32_t* ws = (uint32_t*)d_ws;

    hipMemsetAsync(d_ws, 0, WS_ZERO_BYTES, stream);

    const dim3 hgrid(48, NIMG);
    hist_pass<<<hgrid, 256, 0, stream>>>(dp, dg, vmask, ws, 24, 1);
    select_pass<<<NIMG, 256, 0, stream>>>(ws, 24, intr, posegt, posepred);
    hist_pass<<<hgrid, 256, 0, stream>>>(dp, dg, vmask, ws, 16, 0);
    select_pass<<<NIMG, 256, 0, stream>>>(ws, 16, intr, posegt, posepred);
    hist_pass<<<hgrid, 256, 0, stream>>>(dp, dg, vmask, ws, 8, 0);
    select_pass<<<NIMG, 256, 0, stream>>>(ws, 8, intr, posegt, posepred);
    hist_pass<<<hgrid, 256, 0, stream>>>(dp, dg, vmask, ws, 0, 0);
    select_pass<<<NIMG, 256, 0, stream>>>(ws, 0, intr, posegt, posepred);

    main_loss<<<dim3(192, NIMG), 256, 0, stream>>>(dp, dg, vmask, pts_pred, intr, posegt, ws);
    finalize_k<<<1, 256, 0, stream>>>(ws, out);
}

// Round 3
// 102.234 us; speedup vs baseline: 4.6963x; 1.4384x over previous
//
#include <hip/hip_runtime.h>
#include <stdint.h>

#define H_ 384
#define W_ 512
#define HW_ (H_ * W_)
#define NIMG 32
#define EPSF 1e-6f
#define NPARTS (192 * 32)
#define SENT 0xFFFFFFFFu

// ---- workspace layout (bytes) ----
#define OFF_ACC    0        // 8 doubles: [5]=pose_sum
#define OFF_MSUM   64       // 32 ints
#define OFF_FCNT   192      // 32 ints
#define OFF_KREM   320      // 32 ints
#define OFF_PREFIX 448      // 32 uints
#define OFF_SCALE  576      // 32 floats
#define OFF_HIST   768      // 32 * 2048 uints = 262144
#define OFF_PART   262912   // NPARTS*5 floats = 122880 (fully overwritten)
#define OFF_KEYS   385792   // NIMG*HW u32 = 25165824 (fully overwritten)
#define WS_ZERO_BYTES 262912
#define WS_KEYS_NEED  (385792ull + (unsigned long long)NIMG * HW_ * 4ull)

__device__ __forceinline__ bool finitef(float x) {
    return ((__float_as_uint(x) >> 23) & 0xFFu) != 0xFFu;
}

// ---------------- pass 1: keys + hist bits[31:21] + msum/fcnt ----------------
__global__ __launch_bounds__(256) void hist0_k(
    const float* __restrict__ dp, const float* __restrict__ dg,
    const uint8_t* __restrict__ vmask, uint32_t* __restrict__ keys,
    uint32_t* __restrict__ ws_u32, int write_keys)
{
    __shared__ uint32_t lh[2048];
    __shared__ int lmsum, lfcnt;
    const int img = blockIdx.y;
    const int t = threadIdx.x;
    for (int b = t; b < 2048; b += 256) lh[b] = 0;
    if (t == 0) { lmsum = 0; lfcnt = 0; }
    __syncthreads();

    const size_t base = (size_t)img * HW_;
    const float* dpi = dp + base;
    const float* dgi = dg + base;
    const uint8_t* mi = vmask + base;
    uint32_t* ki = write_keys ? keys + base : nullptr;

    int m2c = 0, fmc = 0;
    int curbin = -1; uint32_t rcnt = 0;

    for (int c = 0; c < 4; ++c) {
        const int pix = blockIdx.x * 4096 + c * 1024 + t * 4;
        const float4 v_dp = *reinterpret_cast<const float4*>(dpi + pix);
        const float4 v_dg = *reinterpret_cast<const float4*>(dgi + pix);
        const uchar4 v_m  = *reinterpret_cast<const uchar4*>(mi + pix);
        const float dpa[4] = {v_dp.x, v_dp.y, v_dp.z, v_dp.w};
        const float dga[4] = {v_dg.x, v_dg.y, v_dg.z, v_dg.w};
        const uint8_t ma[4] = {v_m.x, v_m.y, v_m.z, v_m.w};
        uint32_t kout[4];
#pragma unroll
        for (int e = 0; e < 4; ++e) {
            const float dgv = dga[e], dpv = dpa[e];
            const bool vm = ma[e] && finitef(dgv) && (dgv > 1e-6f);
            const bool m2 = vm && finitef(dpv) && (dpv > EPSF);
            const float ratio = dpv / fmaxf(dgv, EPSF);
            const bool fm = m2 && finitef(ratio);
            m2c += (int)m2; fmc += (int)fm;
            const uint32_t key = fm ? __float_as_uint(ratio) : SENT;
            kout[e] = key;
            if (fm) {
                const int bin = (int)(key >> 21);
                if (bin == curbin) { rcnt++; }
                else {
                    if (curbin >= 0) atomicAdd(&lh[curbin], rcnt);
                    curbin = bin; rcnt = 1;
                }
            }
        }
        if (write_keys)
            *reinterpret_cast<uint4*>(ki + pix) = make_uint4(kout[0], kout[1], kout[2], kout[3]);
    }
    if (curbin >= 0) atomicAdd(&lh[curbin], rcnt);

    for (int o = 32; o > 0; o >>= 1) { m2c += __shfl_down(m2c, o); fmc += __shfl_down(fmc, o); }
    if ((t & 63) == 0) { atomicAdd(&lmsum, m2c); atomicAdd(&lfcnt, fmc); }
    __syncthreads();

    uint32_t* g_hist = ws_u32 + OFF_HIST / 4 + img * 2048;
    for (int b = t; b < 2048; b += 256)
        if (lh[b]) atomicAdd(&g_hist[b], lh[b]);
    if (t == 0) {
        atomicAdd(((int*)(ws_u32 + OFF_MSUM / 4)) + img, lmsum);
        atomicAdd(((int*)(ws_u32 + OFF_FCNT / 4)) + img, lfcnt);
    }
}

// ---------------- passes 2/3 ----------------
template<bool USE_KEYS>
__global__ __launch_bounds__(256) void histN_k(
    const float* __restrict__ dp, const float* __restrict__ dg,
    const uint8_t* __restrict__ vmask, const uint32_t* __restrict__ keys,
    uint32_t* __restrict__ ws_u32, int pass)
{
    __shared__ uint32_t lh[2048];
    const int img = blockIdx.y;
    const int t = threadIdx.x;
    for (int b = t; b < 2048; b += 256) lh[b] = 0;
    __syncthreads();

    const uint32_t pref = (ws_u32 + OFF_PREFIX / 4)[img];
    const int mshift = (pass == 1) ? 21 : 10;
    const int bshift = (pass == 1) ? 10 : 0;
    const uint32_t bmask = (pass == 1) ? 2047u : 1023u;
    const uint32_t pm = pref >> mshift;

    const size_t base = (size_t)img * HW_;
    int curbin = -1; uint32_t rcnt = 0;

    for (int c = 0; c < 4; ++c) {
        const int pix = blockIdx.x * 4096 + c * 1024 + t * 4;
        uint32_t k4[4];
        if constexpr (USE_KEYS) {
            const uint4 kv = *reinterpret_cast<const uint4*>(keys + base + pix);
            k4[0] = kv.x; k4[1] = kv.y; k4[2] = kv.z; k4[3] = kv.w;
        } else {
            const float4 v_dp = *reinterpret_cast<const float4*>(dp + base + pix);
            const float4 v_dg = *reinterpret_cast<const float4*>(dg + base + pix);
            const uchar4 v_m  = *reinterpret_cast<const uchar4*>(vmask + base + pix);
            const float dpa[4] = {v_dp.x, v_dp.y, v_dp.z, v_dp.w};
            const float dga[4] = {v_dg.x, v_dg.y, v_dg.z, v_dg.w};
            const uint8_t ma[4] = {v_m.x, v_m.y, v_m.z, v_m.w};
#pragma unroll
            for (int e = 0; e < 4; ++e) {
                const float dgv = dga[e], dpv = dpa[e];
                const bool vm = ma[e] && finitef(dgv) && (dgv > 1e-6f);
                const bool m2 = vm && finitef(dpv) && (dpv > EPSF);
                const float ratio = dpv / fmaxf(dgv, EPSF);
                const bool fm = m2 && finitef(ratio);
                k4[e] = fm ? __float_as_uint(ratio) : SENT;
            }
        }
#pragma unroll
        for (int e = 0; e < 4; ++e) {
            const uint32_t key = k4[e];
            if ((key >> mshift) == pm) {
                const int bin = (int)((key >> bshift) & bmask);
                if (bin == curbin) { rcnt++; }
                else {
                    if (curbin >= 0) atomicAdd(&lh[curbin], rcnt);
                    curbin = bin; rcnt = 1;
                }
            }
        }
    }
    if (curbin >= 0) atomicAdd(&lh[curbin], rcnt);
    __syncthreads();

    uint32_t* g_hist = ws_u32 + OFF_HIST / 4 + img * 2048;
    for (int b = t; b < 2048; b += 256)
        if (lh[b]) atomicAdd(&g_hist[b], lh[b]);
}

// ---------------- select (parallel scan; pose loss on final) ----------------
__global__ __launch_bounds__(256) void select_k(
    uint32_t* __restrict__ ws_u32, int shift, int nbins,
    const float* __restrict__ intr, const float* __restrict__ posegt,
    const float* __restrict__ posepred)
{
    const int img = blockIdx.x;
    const int t = threadIdx.x;
    uint32_t* g_hist = ws_u32 + OFF_HIST / 4 + img * 2048;
    const int C = nbins >> 8;
    uint32_t local[8];
    uint32_t cs = 0;
    for (int c = 0; c < C; ++c) { local[c] = g_hist[t * C + c]; cs += local[c]; }

    __shared__ uint32_t sc[256];
    sc[t] = cs; __syncthreads();
    for (int off = 1; off < 256; off <<= 1) {
        const uint32_t v = (t >= off) ? sc[t - off] : 0u;
        __syncthreads();
        sc[t] += v;
        __syncthreads();
    }
    const uint32_t incl = sc[t];
    const uint32_t excl = incl - cs;

    int* g_msum = (int*)(ws_u32 + OFF_MSUM / 4);
    int* g_fcnt = (int*)(ws_u32 + OFF_FCNT / 4);
    int* g_krem = (int*)(ws_u32 + OFF_KREM / 4);
    uint32_t* g_prefix = ws_u32 + OFF_PREFIX / 4;
    const int fcnt = g_fcnt[img];

    __shared__ float smed;
    if (t == 0) smed = 1.0f;
    __syncthreads();

    const uint32_t k = (uint32_t)((shift == 21) ? max((fcnt - 1) / 2, 0) : g_krem[img]);
    if (k >= excl && k < incl) {
        uint32_t cum = excl;
        for (int c = 0; c < C; ++c) {
            if (cum + local[c] > k) {
                const uint32_t bin = (uint32_t)(t * C + c);
                g_krem[img] = (int)(k - cum);
                const uint32_t np = (shift == 21) ? (bin << 21)
                                                  : (g_prefix[img] | (bin << shift));
                g_prefix[img] = np;
                if (shift == 0) smed = __uint_as_float(np);
                break;
            }
            cum += local[c];
        }
    }
    __syncthreads();

    if (shift == 0 && t == 0) {
        float sc_ = fminf(fmaxf(smed, 0.001f), 1000.0f);
        if (g_msum[img] < 16 || fcnt == 0) sc_ = 1.0f;
        ((float*)(ws_u32 + OFF_SCALE / 4))[img] = sc_;

        const float* p = posegt + img * 16;
        const float m00 = p[0], m01 = p[1], m02 = p[2], tx = p[3];
        const float m10 = p[4], m11 = p[5], m12 = p[6], ty = p[7];
        const float m20 = p[8], m21 = p[9], m22 = p[10], tz = p[11];
        float qa[4];
        qa[0] = sqrtf(fmaxf(1.0f + m00 + m11 + m22, 0.0f));
        qa[1] = sqrtf(fmaxf(1.0f + m00 - m11 - m22, 0.0f));
        qa[2] = sqrtf(fmaxf(1.0f - m00 + m11 - m22, 0.0f));
        qa[3] = sqrtf(fmaxf(1.0f - m00 - m11 + m22, 0.0f));
        int best = 0; float bv = qa[0];
        for (int i2 = 1; i2 < 4; ++i2) if (qa[i2] > bv) { bv = qa[i2]; best = i2; }
        float c0, c1, c2, c3;
        if (best == 0)      { c0 = qa[0]*qa[0]; c1 = m21 - m12;   c2 = m02 - m20;   c3 = m10 - m01; }
        else if (best == 1) { c0 = m21 - m12;   c1 = qa[1]*qa[1]; c2 = m10 + m01;   c3 = m02 + m20; }
        else if (best == 2) { c0 = m02 - m20;   c1 = m10 + m01;   c2 = qa[2]*qa[2]; c3 = m12 + m21; }
        else                { c0 = m10 - m01;   c1 = m20 + m02;   c2 = m21 + m12;   c3 = qa[3]*qa[3]; }
        const float denom = 2.0f * fmaxf(qa[best], 0.1f);
        float q0 = c0 / denom, q1 = c1 / denom, q2 = c2 / denom, q3 = c3 / denom;
        if (q0 < 0.0f) { q0 = -q0; q1 = -q1; q2 = -q2; q3 = -q3; }
        const float fx = intr[img * 9 + 0], fy = intr[img * 9 + 4];
        const float fovh = 2.0f * atanf((H_ * 0.5f) / fy);
        const float fovw = 2.0f * atanf((W_ * 0.5f) / fx);
        const float pg[9] = {tx * sc_, ty * sc_, tz * sc_, q0, q1, q2, q3, fovh, fovw};
        const float* ppred = posepred + img * 9;
        float s = 0.0f;
        for (int i2 = 0; i2 < 9; ++i2) {
            const float d = fabsf(ppred[i2] - pg[i2]);
            s += (d < 1.0f) ? 0.5f * d * d : d - 0.5f;
        }
        atomicAdd((double*)(ws_u32 + OFF_ACC / 4) + 5, (double)s);
    }

    for (int b = t; b < 2048; b += 256) g_hist[b] = 0;
}

// ---------------- fused main loss pass ----------------
__global__ __launch_bounds__(256) void main_loss(
    const float* __restrict__ dp, const float* __restrict__ dg,
    const uint8_t* __restrict__ vmask, const float* __restrict__ pts_pred,
    const float* __restrict__ intr, const float* __restrict__ posegt,
    uint32_t* __restrict__ ws_u32)
{
    const int img = blockIdx.y;
    const int t = threadIdx.x;
    __shared__ float sP[17];
    if (t == 0) {
        const float* p = posegt + img * 16;
        sP[0] = p[0]; sP[1] = p[1]; sP[2] = p[2];  sP[9]  = p[3];
        sP[3] = p[4]; sP[4] = p[5]; sP[5] = p[6];  sP[10] = p[7];
        sP[6] = p[8]; sP[7] = p[9]; sP[8] = p[10]; sP[11] = p[11];
        sP[12] = intr[img * 9 + 0]; sP[13] = intr[img * 9 + 4];
        sP[14] = intr[img * 9 + 2]; sP[15] = intr[img * 9 + 5];
        sP[16] = ((const float*)(ws_u32 + OFF_SCALE / 4))[img];
    }
    __syncthreads();
    const float R00 = sP[0], R01 = sP[1], R02 = sP[2];
    const float R10 = sP[3], R11 = sP[4], R12 = sP[5];
    const float R20 = sP[6], R21 = sP[7], R22 = sP[8];
    const float T0 = sP[9], T1 = sP[10], T2 = sP[11];
    const float inv_fx = 1.0f / fmaxf(sP[12], EPSF);
    const float inv_fy = 1.0f / fmaxf(sP[13], EPSF);
    const float cx = sP[14], cy = sP[15];
    const float sc = sP[16];

    const size_t base = (size_t)img * HW_;
    const int pix0 = (blockIdx.x * 256 + t) * 4;
    const int i = pix0 >> 9;
    const int j0 = pix0 & 511;
    const float* dpi = dp + base;
    const float* dgi = dg + base;

    const float4 v_dp = *reinterpret_cast<const float4*>(dpi + pix0);
    const float4 v_dg = *reinterpret_cast<const float4*>(dgi + pix0);
    const uchar4 v_m  = *reinterpret_cast<const uchar4*>(vmask + base + pix0);
    const float4 ppA = *reinterpret_cast<const float4*>(pts_pred + (base + pix0) * 3);
    const float4 ppB = *reinterpret_cast<const float4*>(pts_pred + (base + pix0) * 3 + 4);
    const float4 ppC = *reinterpret_cast<const float4*>(pts_pred + (base + pix0) * 3 + 8);

    const int im = (i > 0) ? i - 1 : 0;
    const int ip = (i < H_ - 1) ? i + 1 : i;
    const int jme = (j0 > 0) ? j0 - 1 : 0;
    const int jpe = (j0 + 4 < W_) ? j0 + 4 : W_ - 1;
    const float4 dpU = *reinterpret_cast<const float4*>(dpi + im * W_ + j0);
    const float4 dpD = *reinterpret_cast<const float4*>(dpi + ip * W_ + j0);
    const float4 dgU = *reinterpret_cast<const float4*>(dgi + im * W_ + j0);
    const float4 dgD = *reinterpret_cast<const float4*>(dgi + ip * W_ + j0);
    const float dpLe = dpi[i * W_ + jme], dpRe = dpi[i * W_ + jpe];
    const float dgLe = dgi[i * W_ + jme], dgRe = dgi[i * W_ + jpe];

    const float ppv[12] = {ppA.x, ppA.y, ppA.z, ppA.w, ppB.x, ppB.y, ppB.z, ppB.w,
                           ppC.x, ppC.y, ppC.z, ppC.w};
    const float dpa[4] = {v_dp.x, v_dp.y, v_dp.z, v_dp.w};
    const float dga[4] = {v_dg.x, v_dg.y, v_dg.z, v_dg.w};
    const float dpUa[4] = {dpU.x, dpU.y, dpU.z, dpU.w};
    const float dpDa[4] = {dpD.x, dpD.y, dpD.z, dpD.w};
    const float dgUa[4] = {dgU.x, dgU.y, dgU.z, dgU.w};
    const float dgDa[4] = {dgD.x, dgD.y, dgD.z, dgD.w};
    const uint8_t ma[4] = {v_m.x, v_m.y, v_m.z, v_m.w};

    const float ay   = ((float)i - cy) * inv_fy;
    const float ay_m = ((float)(i - 1) - cy) * inv_fy;
    const float ay_p = ((float)(i + 1) - cy) * inv_fy;
    const bool row_int = (i >= 1) && (i <= H_ - 2);

    float dsum = 0.0f, psum = 0.0f, nsum = 0.0f;
    float vcnt = 0.0f, ncnt = 0.0f;

#pragma unroll
    for (int e = 0; e < 4; ++e) {
        const int j = j0 + e;
        const float dgv = dga[e], dpv = dpa[e];
        const bool vm = ma[e] && finitef(dgv) && (dgv > 1e-6f);
        const bool nm = vm && row_int && (j >= 1) && (j <= W_ - 2);
        vcnt += vm ? 1.0f : 0.0f;
        ncnt += nm ? 1.0f : 0.0f;

        const float dal = dgv * sc;
        dsum += vm ? fabsf(dpv - dal) : 0.0f;
        const float ax = ((float)j - cx) * inv_fx;
        const float cxx = ax * dal, cyy = ay * dal, czz = dal;
        const float wx = R00 * cxx + R01 * cyy + R02 * czz + T0;
        const float wy = R10 * cxx + R11 * cyy + R12 * czz + T1;
        const float wz = R20 * cxx + R21 * cyy + R22 * czz + T2;
        const float pl = fabsf(ppv[3 * e] - wx) + fabsf(ppv[3 * e + 1] - wy)
                       + fabsf(ppv[3 * e + 2] - wz);
        psum += vm ? pl : 0.0f;

        // ---- normals via single rsq ----
        const float pdL = (e == 0) ? dpLe : dpa[e - 1];
        const float pdR = (e == 3) ? dpRe : dpa[e + 1];
        const float gdL = (e == 0) ? dgLe : dga[e - 1];
        const float gdR = (e == 3) ? dgRe : dga[e + 1];
        const float pdU = dpUa[e], pdD = dpDa[e];
        const float gdU = dgUa[e], gdD = dgDa[e];
        const float ax_m = ((float)(j - 1) - cx) * inv_fx;
        const float ax_p = ((float)(j + 1) - cx) * inv_fx;

        float cpx, cpy, cpz, cgx, cgy, cgz;
        {
            const float dRL = pdR - pdL, dDU = pdD - pdU;
            const float fxx = ax_p * pdR - ax_m * pdL;
            const float fxy = ay * dRL;
            const float fyx = ax * dDU;
            const float fyy = ay_p * pdD - ay_m * pdU;
            cpx = fyy * dRL - dDU * fxy;
            cpy = dDU * fxx - fyx * dRL;
            cpz = fyx * fxy - fyy * fxx;
        }
        {
            const float dRL = gdR - gdL, dDU = gdD - gdU;
            const float fxx = ax_p * gdR - ax_m * gdL;
            const float fxy = ay * dRL;
            const float fyx = ax * dDU;
            const float fyy = ay_p * gdD - ay_m * gdU;
            cgx = fyy * dRL - dDU * fxy;
            cgy = dDU * fxx - fyx * dRL;
            cgz = fyx * fxy - fyy * fxx;
        }
        const float np2 = cpx * cpx + cpy * cpy + cpz * cpz;
        const float ng2 = cgx * cgx + cgy * cgy + cgz * cgz;
        const float dpg = cpx * cgx + cpy * cgy + cpz * cgz;
        const float den = fmaxf(np2, 1e-12f) * fmaxf(ng2, 1e-12f);
        float cosv = dpg * __builtin_amdgcn_rsqf(den);
        cosv = fminf(fmaxf(cosv, -1.0f), 1.0f);
        nsum += nm ? (1.0f - cosv) : 0.0f;
    }

    float vals[5] = {vcnt, dsum, psum, nsum, ncnt};
    __shared__ float red[4][5];
    const int wave = t >> 6, lane = t & 63;
#pragma unroll
    for (int q = 0; q < 5; ++q) {
        float v = vals[q];
        for (int o = 32; o > 0; o >>= 1) v += __shfl_down(v, o);
        if (lane == 0) red[wave][q] = v;
    }
    __syncthreads();
    if (t == 0) {
        const int slot = blockIdx.y * gridDim.x + blockIdx.x;
        float* part = (float*)(ws_u32 + OFF_PART / 4) + slot * 5;
#pragma unroll
        for (int q = 0; q < 5; ++q)
            part[q] = red[0][q] + red[1][q] + red[2][q] + red[3][q];
    }
}

// ---------------- finalize ----------------
__global__ __launch_bounds__(256) void finalize_k(const uint32_t* __restrict__ ws_u32,
                                                  float* __restrict__ out)
{
    const float* part = (const float*)(ws_u32 + OFF_PART / 4);
    const int t = threadIdx.x;
    double s[5] = {0, 0, 0, 0, 0};
    for (int slot = t; slot < NPARTS; slot += 256) {
#pragma unroll
        for (int q = 0; q < 5; ++q) s[q] += (double)part[slot * 5 + q];
    }
    __shared__ double red[4][5];
    const int wave = t >> 6, lane = t & 63;
#pragma unroll
    for (int q = 0; q < 5; ++q) {
        double v = s[q];
        for (int o = 32; o > 0; o >>= 1) v += __shfl_down(v, o);
        if (lane == 0) red[wave][q] = v;
    }
    __syncthreads();
    if (t == 0) {
        double tot[5];
#pragma unroll
        for (int q = 0; q < 5; ++q)
            tot[q] = red[0][q] + red[1][q] + red[2][q] + red[3][q];
        const double* acc = (const double*)(ws_u32 + OFF_ACC / 4);
        const double vmc = tot[0];
        const double depth_loss  = tot[1] / fmax(vmc, 1.0);
        const double points_loss = tot[2] / fmax(3.0 * vmc, 1.0);
        const double normal_loss = tot[3] / fmax(tot[4], 1.0);
        const double pose_loss   = acc[5] / 288.0;
        out[0] = (float)(pose_loss + depth_loss + points_loss + 0.1 * normal_loss);
    }
}

extern "C" void kernel_launch(void* const* d_in, const int* in_sizes, int n_in,
                              void* d_out, int out_size, void* d_ws, size_t ws_size,
                              hipStream_t stream)
{
    const float*   dp       = (const float*)d_in[0];
    const float*   pts_pred = (const float*)d_in[1];
    const float*   posepred = (const float*)d_in[2];
    const float*   dg       = (const float*)d_in[3];
    const float*   intr     = (const float*)d_in[4];
    const float*   posegt   = (const float*)d_in[5];
    const uint8_t* vmask    = (const uint8_t*)d_in[6];
    float* out = (float*)d_out;
    uint32_t* ws = (uint32_t*)d_ws;

    const bool use_keys = ws_size >= (size_t)WS_KEYS_NEED;
    uint32_t* keys = use_keys ? (uint32_t*)((char*)d_ws + OFF_KEYS) : nullptr;

    hipMemsetAsync(d_ws, 0, WS_ZERO_BYTES, stream);

    const dim3 hgrid(48, NIMG);
    hist0_k<<<hgrid, 256, 0, stream>>>(dp, dg, vmask, keys, ws, use_keys ? 1 : 0);
    select_k<<<NIMG, 256, 0, stream>>>(ws, 21, 2048, intr, posegt, posepred);
    if (use_keys) {
        histN_k<true><<<hgrid, 256, 0, stream>>>(dp, dg, vmask, keys, ws, 1);
        select_k<<<NIMG, 256, 0, stream>>>(ws, 10, 2048, intr, posegt, posepred);
        histN_k<true><<<hgrid, 256, 0, stream>>>(dp, dg, vmask, keys, ws, 2);
        select_k<<<NIMG, 256, 0, stream>>>(ws, 0, 1024, intr, posegt, posepred);
    } else {
        histN_k<false><<<hgrid, 256, 0, stream>>>(dp, dg, vmask, keys, ws, 1);
        select_k<<<NIMG, 256, 0, stream>>>(ws, 10, 2048, intr, posegt, posepred);
        histN_k<false><<<hgrid, 256, 0, stream>>>(dp, dg, vmask, keys, ws, 2);
        select_k<<<NIMG, 256, 0, stream>>>(ws, 0, 1024, intr, posegt, posepred);
    }

    main_loss<<<dim3(192, NIMG), 256, 0, stream>>>(dp, dg, vmask, pts_pred, intr, posegt, ws);
    finalize_k<<<1, 256, 0, stream>>>(ws, out);
}

// Round 4
// 84.451 us; speedup vs baseline: 5.6853x; 1.2106x over previous
//
#include <hip/hip_runtime.h>
#include <stdint.h>

#define H_ 384
#define W_ 512
#define HW_ (H_ * W_)
#define NIMG 32
#define EPSF 1e-6f
#define HBLK 16            // hist blocks per image
#define HTHR 512           // threads per hist block
#define PXB (HW_ / HBLK)   // 12288 px per hist block
#define CITER (PXB / (HTHR * 4))  // 6
#define NPARTS (192 * 32)
#define SENT 0xFFFFFFFFu

// ---- workspace layout (u32 indices). NOTHING needs pre-zeroing: every ----
// ---- buffer is fully overwritten before being read, every call.       ----
#define OFF_MSUM   0                      // 32 i32   (written by select<21>)
#define OFF_FCNT   32                     // 32 i32
#define OFF_KREM   64                     // 32 i32   (written by each select)
#define OFF_PREFIX 96                     // 32 u32
#define OFF_SCALE  128                    // 32 f32   (written by select<0>)
#define OFF_POSE   160                    // 32 f32   (written by select<0>)
#define OFF_PMF    192                    // 32*16*2 i32 = 1024 (hist0 partials)
#define OFF_PART   1216                   // 6144*5 f32 = 30720 (main_loss partials)
#define OFF_PHIST  31936                  // 32*16*2048 u32 = 1048576 (hist partials)
#define OFF_KEYS   (OFF_PHIST + NIMG * HBLK * 2048)   // 32*HW u32
#define WS_KEYS_NEED ((unsigned long long)(OFF_KEYS + (size_t)NIMG * HW_) * 4ull)

__device__ __forceinline__ bool finitef(float x) {
    return ((__float_as_uint(x) >> 23) & 0xFFu) != 0xFFu;
}

// ---------------- pass 1: keys + partial hist of bits[31:21] (ballot-dedup) ----------------
__global__ __launch_bounds__(HTHR) void hist0_k(
    const float* __restrict__ dp, const float* __restrict__ dg,
    const uint8_t* __restrict__ vmask, uint32_t* __restrict__ keys,
    uint32_t* __restrict__ ws, int write_keys)
{
    __shared__ uint32_t lh[2048];
    __shared__ int sm[8], sf[8];
    const int img = blockIdx.y, blk = blockIdx.x, t = threadIdx.x;
    for (int b = t; b < 2048; b += HTHR) lh[b] = 0;
    __syncthreads();

    const size_t base = (size_t)img * HW_;
    const float* dpi = dp + base;
    const float* dgi = dg + base;
    const uint8_t* mi = vmask + base;
    uint32_t* ki = keys + base;

    int m2c = 0, fmc = 0;

    for (int c = 0; c < CITER; ++c) {
        const int pix = blk * PXB + c * (HTHR * 4) + t * 4;
        const float4 v_dp = *reinterpret_cast<const float4*>(dpi + pix);
        const float4 v_dg = *reinterpret_cast<const float4*>(dgi + pix);
        const uchar4 v_m  = *reinterpret_cast<const uchar4*>(mi + pix);
        const float dpa[4] = {v_dp.x, v_dp.y, v_dp.z, v_dp.w};
        const float dga[4] = {v_dg.x, v_dg.y, v_dg.z, v_dg.w};
        const uint8_t ma[4] = {v_m.x, v_m.y, v_m.z, v_m.w};
        uint32_t kout[4]; int bins[4]; bool fms[4];
#pragma unroll
        for (int e = 0; e < 4; ++e) {
            const float dgv = dga[e], dpv = dpa[e];
            const bool vm = ma[e] && finitef(dgv) && (dgv > 1e-6f);
            const bool m2 = vm && finitef(dpv) && (dpv > EPSF);
            const float ratio = dpv / fmaxf(dgv, EPSF);
            const bool fm = m2 && finitef(ratio);
            m2c += (int)m2; fmc += (int)fm;
            const uint32_t key = fm ? __float_as_uint(ratio) : SENT;
            kout[e] = key;
            bins[e] = (int)(key >> 21);
            fms[e] = fm;
        }
        if (write_keys)
            *reinterpret_cast<uint4*>(ki + pix) = make_uint4(kout[0], kout[1], kout[2], kout[3]);

        // wave-aggregated histogram add: iterate distinct bins in the wave,
        // one atomicAdd(count) per distinct bin by the lead lane.
#pragma unroll
        for (int e = 0; e < 4; ++e) {
            const bool fm = fms[e];
            const int bin = bins[e];
            unsigned long long todo = __ballot(fm);
            while (todo) {
                const int lead = (int)__ffsll(todo) - 1;
                const int lbin = __shfl(bin, lead);
                const unsigned long long same = __ballot(fm && (bin == lbin));
                if ((t & 63) == lead)
                    atomicAdd(&lh[lbin], (uint32_t)__popcll(same));
                todo &= ~same;
            }
        }
    }

    // per-block msum/fcnt partials
    for (int o = 32; o > 0; o >>= 1) { m2c += __shfl_down(m2c, o); fmc += __shfl_down(fmc, o); }
    if ((t & 63) == 0) { sm[t >> 6] = m2c; sf[t >> 6] = fmc; }
    __syncthreads();
    if (t == 0) {
        int M = 0, F = 0;
        for (int w = 0; w < 8; ++w) { M += sm[w]; F += sf[w]; }
        int* pmf = (int*)(ws + OFF_PMF) + (img * HBLK + blk) * 2;
        pmf[0] = M; pmf[1] = F;
    }

    // flush LDS hist -> per-block partial (plain stores, fully overwrites)
    uint32_t* phb = ws + OFF_PHIST + (size_t)(img * HBLK + blk) * 2048;
    for (int b = t; b < 2048; b += HTHR) phb[b] = lh[b];
}

// ---------------- passes 2/3: plain LDS atomics (bins spread after prefix match) ----------------
template<bool USE_KEYS>
__global__ __launch_bounds__(HTHR) void histN_k(
    const float* __restrict__ dp, const float* __restrict__ dg,
    const uint8_t* __restrict__ vmask, const uint32_t* __restrict__ keys,
    uint32_t* __restrict__ ws, int pass)
{
    __shared__ uint32_t lh[2048];
    const int img = blockIdx.y, blk = blockIdx.x, t = threadIdx.x;
    for (int b = t; b < 2048; b += HTHR) lh[b] = 0;
    __syncthreads();

    const uint32_t pref = (ws + OFF_PREFIX)[img];
    const int mshift = (pass == 1) ? 21 : 10;
    const int bshift = (pass == 1) ? 10 : 0;
    const uint32_t bmask = (pass == 1) ? 2047u : 1023u;
    const uint32_t pm = pref >> mshift;

    const size_t base = (size_t)img * HW_;

    for (int c = 0; c < CITER; ++c) {
        const int pix = blk * PXB + c * (HTHR * 4) + t * 4;
        uint32_t k4[4];
        if constexpr (USE_KEYS) {
            const uint4 kv = *reinterpret_cast<const uint4*>(keys + base + pix);
            k4[0] = kv.x; k4[1] = kv.y; k4[2] = kv.z; k4[3] = kv.w;
        } else {
            const float4 v_dp = *reinterpret_cast<const float4*>(dp + base + pix);
            const float4 v_dg = *reinterpret_cast<const float4*>(dg + base + pix);
            const uchar4 v_m  = *reinterpret_cast<const uchar4*>(vmask + base + pix);
            const float dpa[4] = {v_dp.x, v_dp.y, v_dp.z, v_dp.w};
            const float dga[4] = {v_dg.x, v_dg.y, v_dg.z, v_dg.w};
            const uint8_t ma[4] = {v_m.x, v_m.y, v_m.z, v_m.w};
#pragma unroll
            for (int e = 0; e < 4; ++e) {
                const float dgv = dga[e], dpv = dpa[e];
                const bool vm = ma[e] && finitef(dgv) && (dgv > 1e-6f);
                const bool m2 = vm && finitef(dpv) && (dpv > EPSF);
                const float ratio = dpv / fmaxf(dgv, EPSF);
                const bool fm = m2 && finitef(ratio);
                k4[e] = fm ? __float_as_uint(ratio) : SENT;
            }
        }
#pragma unroll
        for (int e = 0; e < 4; ++e) {
            const uint32_t key = k4[e];
            if ((key >> mshift) == pm)
                atomicAdd(&lh[(key >> bshift) & bmask], 1u);
        }
    }
    __syncthreads();

    uint32_t* phb = ws + OFF_PHIST + (size_t)(img * HBLK + blk) * 2048;
    for (int b = t; b < 2048; b += HTHR) phb[b] = lh[b];
}

// ---------------- select: sum partials, scan, pick k-th; pose on final ----------------
template<int SHIFT, int C>
__global__ __launch_bounds__(256) void select_k(
    uint32_t* __restrict__ ws,
    const float* __restrict__ intr, const float* __restrict__ posegt,
    const float* __restrict__ posepred)
{
    const int img = blockIdx.x;
    const int t = threadIdx.x;

    // sum the 16 per-block partials for my C bins
    const uint32_t* ph = ws + OFF_PHIST + (size_t)img * HBLK * 2048;
    uint32_t local[C];
#pragma unroll
    for (int c = 0; c < C; ++c) local[c] = 0;
    for (int b = 0; b < HBLK; ++b) {
        const uint32_t* row = ph + b * 2048 + t * C;
#pragma unroll
        for (int c = 0; c < C; ++c) local[c] += row[c];
    }
    uint32_t cs = 0;
#pragma unroll
    for (int c = 0; c < C; ++c) cs += local[c];

    // block scan
    __shared__ uint32_t sscan[256];
    sscan[t] = cs; __syncthreads();
    for (int off = 1; off < 256; off <<= 1) {
        const uint32_t v = (t >= off) ? sscan[t - off] : 0u;
        __syncthreads();
        sscan[t] += v;
        __syncthreads();
    }
    const uint32_t incl = sscan[t];
    const uint32_t excl = incl - cs;

    __shared__ int s_bin, s_krem, s_fcnt;
    if (t == 0) {
        s_bin = 0; s_krem = 0;
        if (SHIFT == 21) {
            const int* pmf = (const int*)(ws + OFF_PMF) + img * HBLK * 2;
            int M = 0, F = 0;
            for (int b = 0; b < HBLK; ++b) { M += pmf[2 * b]; F += pmf[2 * b + 1]; }
            ((int*)(ws + OFF_MSUM))[img] = M;
            ((int*)(ws + OFF_FCNT))[img] = F;
            s_fcnt = F;
        }
    }
    __syncthreads();

    const int fcnt = (SHIFT == 21) ? s_fcnt : ((const int*)(ws + OFF_FCNT))[img];
    const uint32_t k = (uint32_t)((SHIFT == 21) ? max((fcnt - 1) / 2, 0)
                                                : ((const int*)(ws + OFF_KREM))[img]);
    if (k >= excl && k < incl) {       // exactly one thread (if any counts)
        uint32_t cum = excl;
#pragma unroll
        for (int c = 0; c < C; ++c) {
            if (cum + local[c] > k) { s_bin = t * C + c; s_krem = (int)(k - cum); break; }
            cum += local[c];
        }
    }
    __syncthreads();

    if (t == 0) {
        uint32_t* gpref = ws + OFF_PREFIX;
        const uint32_t np = (SHIFT == 21) ? ((uint32_t)s_bin << 21)
                                          : (gpref[img] | ((uint32_t)s_bin << SHIFT));
        gpref[img] = np;
        ((int*)(ws + OFF_KREM))[img] = s_krem;

        if (SHIFT == 0) {
            const float med = __uint_as_float(np);
            float sc_ = fminf(fmaxf(med, 0.001f), 1000.0f);
            const int msum = ((const int*)(ws + OFF_MSUM))[img];
            if (msum < 16 || fcnt == 0) sc_ = 1.0f;
            ((float*)(ws + OFF_SCALE))[img] = sc_;

            // ---- pose encoding + smooth L1 ----
            const float* p = posegt + img * 16;
            const float m00 = p[0], m01 = p[1], m02 = p[2], tx = p[3];
            const float m10 = p[4], m11 = p[5], m12 = p[6], ty = p[7];
            const float m20 = p[8], m21 = p[9], m22 = p[10], tz = p[11];
            float qa[4];
            qa[0] = sqrtf(fmaxf(1.0f + m00 + m11 + m22, 0.0f));
            qa[1] = sqrtf(fmaxf(1.0f + m00 - m11 - m22, 0.0f));
            qa[2] = sqrtf(fmaxf(1.0f - m00 + m11 - m22, 0.0f));
            qa[3] = sqrtf(fmaxf(1.0f - m00 - m11 + m22, 0.0f));
            int best = 0; float bv = qa[0];
            for (int i2 = 1; i2 < 4; ++i2) if (qa[i2] > bv) { bv = qa[i2]; best = i2; }
            float c0, c1, c2, c3;
            if (best == 0)      { c0 = qa[0]*qa[0]; c1 = m21 - m12;   c2 = m02 - m20;   c3 = m10 - m01; }
            else if (best == 1) { c0 = m21 - m12;   c1 = qa[1]*qa[1]; c2 = m10 + m01;   c3 = m02 + m20; }
            else if (best == 2) { c0 = m02 - m20;   c1 = m10 + m01;   c2 = qa[2]*qa[2]; c3 = m12 + m21; }
            else                { c0 = m10 - m01;   c1 = m20 + m02;   c2 = m21 + m12;   c3 = qa[3]*qa[3]; }
            const float denom = 2.0f * fmaxf(qa[best], 0.1f);
            float q0 = c0 / denom, q1 = c1 / denom, q2 = c2 / denom, q3 = c3 / denom;
            if (q0 < 0.0f) { q0 = -q0; q1 = -q1; q2 = -q2; q3 = -q3; }
            const float fx = intr[img * 9 + 0], fy = intr[img * 9 + 4];
            const float fovh = 2.0f * atanf((H_ * 0.5f) / fy);
            const float fovw = 2.0f * atanf((W_ * 0.5f) / fx);
            const float pg[9] = {tx * sc_, ty * sc_, tz * sc_, q0, q1, q2, q3, fovh, fovw};
            const float* ppred = posepred + img * 9;
            float s = 0.0f;
            for (int i2 = 0; i2 < 9; ++i2) {
                const float d = fabsf(ppred[i2] - pg[i2]);
                s += (d < 1.0f) ? 0.5f * d * d : d - 0.5f;
            }
            ((float*)(ws + OFF_POSE))[img] = s;   // plain store, no atomic
        }
    }
}

// ---------------- fused main loss pass ----------------
__global__ __launch_bounds__(256) void main_loss(
    const float* __restrict__ dp, const float* __restrict__ dg,
    const uint8_t* __restrict__ vmask, const float* __restrict__ pts_pred,
    const float* __restrict__ intr, const float* __restrict__ posegt,
    uint32_t* __restrict__ ws)
{
    const int img = blockIdx.y;
    const int t = threadIdx.x;
    __shared__ float sP[17];
    if (t == 0) {
        const float* p = posegt + img * 16;
        sP[0] = p[0]; sP[1] = p[1]; sP[2] = p[2];  sP[9]  = p[3];
        sP[3] = p[4]; sP[4] = p[5]; sP[5] = p[6];  sP[10] = p[7];
        sP[6] = p[8]; sP[7] = p[9]; sP[8] = p[10]; sP[11] = p[11];
        sP[12] = intr[img * 9 + 0]; sP[13] = intr[img * 9 + 4];
        sP[14] = intr[img * 9 + 2]; sP[15] = intr[img * 9 + 5];
        sP[16] = ((const float*)(ws + OFF_SCALE))[img];
    }
    __syncthreads();
    const float R00 = sP[0], R01 = sP[1], R02 = sP[2];
    const float R10 = sP[3], R11 = sP[4], R12 = sP[5];
    const float R20 = sP[6], R21 = sP[7], R22 = sP[8];
    const float T0 = sP[9], T1 = sP[10], T2 = sP[11];
    const float inv_fx = 1.0f / fmaxf(sP[12], EPSF);
    const float inv_fy = 1.0f / fmaxf(sP[13], EPSF);
    const float cx = sP[14], cy = sP[15];
    const float sc = sP[16];

    const size_t base = (size_t)img * HW_;
    const int pix0 = (blockIdx.x * 256 + t) * 4;
    const int i = pix0 >> 9;
    const int j0 = pix0 & 511;
    const float* dpi = dp + base;
    const float* dgi = dg + base;

    const float4 v_dp = *reinterpret_cast<const float4*>(dpi + pix0);
    const float4 v_dg = *reinterpret_cast<const float4*>(dgi + pix0);
    const uchar4 v_m  = *reinterpret_cast<const uchar4*>(vmask + base + pix0);
    const float4 ppA = *reinterpret_cast<const float4*>(pts_pred + (base + pix0) * 3);
    const float4 ppB = *reinterpret_cast<const float4*>(pts_pred + (base + pix0) * 3 + 4);
    const float4 ppC = *reinterpret_cast<const float4*>(pts_pred + (base + pix0) * 3 + 8);

    const int im = (i > 0) ? i - 1 : 0;
    const int ip = (i < H_ - 1) ? i + 1 : i;
    const int jme = (j0 > 0) ? j0 - 1 : 0;
    const int jpe = (j0 + 4 < W_) ? j0 + 4 : W_ - 1;
    const float4 dpU = *reinterpret_cast<const float4*>(dpi + im * W_ + j0);
    const float4 dpD = *reinterpret_cast<const float4*>(dpi + ip * W_ + j0);
    const float4 dgU = *reinterpret_cast<const float4*>(dgi + im * W_ + j0);
    const float4 dgD = *reinterpret_cast<const float4*>(dgi + ip * W_ + j0);
    const float dpLe = dpi[i * W_ + jme], dpRe = dpi[i * W_ + jpe];
    const float dgLe = dgi[i * W_ + jme], dgRe = dgi[i * W_ + jpe];

    const float ppv[12] = {ppA.x, ppA.y, ppA.z, ppA.w, ppB.x, ppB.y, ppB.z, ppB.w,
                           ppC.x, ppC.y, ppC.z, ppC.w};
    const float dpa[4] = {v_dp.x, v_dp.y, v_dp.z, v_dp.w};
    const float dga[4] = {v_dg.x, v_dg.y, v_dg.z, v_dg.w};
    const float dpUa[4] = {dpU.x, dpU.y, dpU.z, dpU.w};
    const float dpDa[4] = {dpD.x, dpD.y, dpD.z, dpD.w};
    const float dgUa[4] = {dgU.x, dgU.y, dgU.z, dgU.w};
    const float dgDa[4] = {dgD.x, dgD.y, dgD.z, dgD.w};
    const uint8_t ma[4] = {v_m.x, v_m.y, v_m.z, v_m.w};

    const float ay   = ((float)i - cy) * inv_fy;
    const float ay_m = ((float)(i - 1) - cy) * inv_fy;
    const float ay_p = ((float)(i + 1) - cy) * inv_fy;
    const bool row_int = (i >= 1) && (i <= H_ - 2);

    float dsum = 0.0f, psum = 0.0f, nsum = 0.0f;
    float vcnt = 0.0f, ncnt = 0.0f;

#pragma unroll
    for (int e = 0; e < 4; ++e) {
        const int j = j0 + e;
        const float dgv = dga[e], dpv = dpa[e];
        const bool vm = ma[e] && finitef(dgv) && (dgv > 1e-6f);
        const bool nm = vm && row_int && (j >= 1) && (j <= W_ - 2);
        vcnt += vm ? 1.0f : 0.0f;
        ncnt += nm ? 1.0f : 0.0f;

        const float dal = dgv * sc;
        dsum += vm ? fabsf(dpv - dal) : 0.0f;
        const float ax = ((float)j - cx) * inv_fx;
        const float cxx = ax * dal, cyy = ay * dal, czz = dal;
        const float wx = R00 * cxx + R01 * cyy + R02 * czz + T0;
        const float wy = R10 * cxx + R11 * cyy + R12 * czz + T1;
        const float wz = R20 * cxx + R21 * cyy + R22 * czz + T2;
        const float pl = fabsf(ppv[3 * e] - wx) + fabsf(ppv[3 * e + 1] - wy)
                       + fabsf(ppv[3 * e + 2] - wz);
        psum += vm ? pl : 0.0f;

        const float pdL = (e == 0) ? dpLe : dpa[e - 1];
        const float pdR = (e == 3) ? dpRe : dpa[e + 1];
        const float gdL = (e == 0) ? dgLe : dga[e - 1];
        const float gdR = (e == 3) ? dgRe : dga[e + 1];
        const float pdU = dpUa[e], pdD = dpDa[e];
        const float gdU = dgUa[e], gdD = dgDa[e];
        const float ax_m = ((float)(j - 1) - cx) * inv_fx;
        const float ax_p = ((float)(j + 1) - cx) * inv_fx;

        float cpx, cpy, cpz, cgx, cgy, cgz;
        {
            const float dRL = pdR - pdL, dDU = pdD - pdU;
            const float fxx = ax_p * pdR - ax_m * pdL;
            const float fxy = ay * dRL;
            const float fyx = ax * dDU;
            const float fyy = ay_p * pdD - ay_m * pdU;
            cpx = fyy * dRL - dDU * fxy;
            cpy = dDU * fxx - fyx * dRL;
            cpz = fyx * fxy - fyy * fxx;
        }
        {
            const float dRL = gdR - gdL, dDU = gdD - gdU;
            const float fxx = ax_p * gdR - ax_m * gdL;
            const float fxy = ay * dRL;
            const float fyx = ax * dDU;
            const float fyy = ay_p * gdD - ay_m * gdU;
            cgx = fyy * dRL - dDU * fxy;
            cgy = dDU * fxx - fyx * dRL;
            cgz = fyx * fxy - fyy * fxx;
        }
        const float np2 = cpx * cpx + cpy * cpy + cpz * cpz;
        const float ng2 = cgx * cgx + cgy * cgy + cgz * cgz;
        const float dpg = cpx * cgx + cpy * cgy + cpz * cgz;
        const float den = fmaxf(np2, 1e-12f) * fmaxf(ng2, 1e-12f);
        float cosv = dpg * __builtin_amdgcn_rsqf(den);
        cosv = fminf(fmaxf(cosv, -1.0f), 1.0f);
        nsum += nm ? (1.0f - cosv) : 0.0f;
    }

    float vals[5] = {vcnt, dsum, psum, nsum, ncnt};
    __shared__ float red[4][5];
    const int wave = t >> 6, lane = t & 63;
#pragma unroll
    for (int q = 0; q < 5; ++q) {
        float v = vals[q];
        for (int o = 32; o > 0; o >>= 1) v += __shfl_down(v, o);
        if (lane == 0) red[wave][q] = v;
    }
    __syncthreads();
    if (t == 0) {
        const int slot = blockIdx.y * gridDim.x + blockIdx.x;
        float* part = (float*)(ws + OFF_PART) + slot * 5;
#pragma unroll
        for (int q = 0; q < 5; ++q)
            part[q] = red[0][q] + red[1][q] + red[2][q] + red[3][q];
    }
}

// ---------------- finalize ----------------
__global__ __launch_bounds__(256) void finalize_k(const uint32_t* __restrict__ ws,
                                                  float* __restrict__ out)
{
    const float* part = (const float*)(ws + OFF_PART);
    const int t = threadIdx.x;
    double s[5] = {0, 0, 0, 0, 0};
    for (int slot = t; slot < NPARTS; slot += 256) {
#pragma unroll
        for (int q = 0; q < 5; ++q) s[q] += (double)part[slot * 5 + q];
    }
    __shared__ double red[4][5];
    const int wave = t >> 6, lane = t & 63;
#pragma unroll
    for (int q = 0; q < 5; ++q) {
        double v = s[q];
        for (int o = 32; o > 0; o >>= 1) v += __shfl_down(v, o);
        if (lane == 0) red[wave][q] = v;
    }
    __syncthreads();
    if (t == 0) {
        double tot[5];
#pragma unroll
        for (int q = 0; q < 5; ++q)
            tot[q] = red[0][q] + red[1][q] + red[2][q] + red[3][q];
        const float* pose = (const float*)(ws + OFF_POSE);
        double ps = 0.0;
        for (int i2 = 0; i2 < NIMG; ++i2) ps += (double)pose[i2];
        const double vmc = tot[0];
        const double depth_loss  = tot[1] / fmax(vmc, 1.0);
        const double points_loss = tot[2] / fmax(3.0 * vmc, 1.0);
        const double normal_loss = tot[3] / fmax(tot[4], 1.0);
        const double pose_loss   = ps / 288.0;
        out[0] = (float)(pose_loss + depth_loss + points_loss + 0.1 * normal_loss);
    }
}

extern "C" void kernel_launch(void* const* d_in, const int* in_sizes, int n_in,
                              void* d_out, int out_size, void* d_ws, size_t ws_size,
                              hipStream_t stream)
{
    const float*   dp       = (const float*)d_in[0];
    const float*   pts_pred = (const float*)d_in[1];
    const float*   posepred = (const float*)d_in[2];
    const float*   dg       = (const float*)d_in[3];
    const float*   intr     = (const float*)d_in[4];
    const float*   posegt   = (const float*)d_in[5];
    const uint8_t* vmask    = (const uint8_t*)d_in[6];
    float* out = (float*)d_out;
    uint32_t* ws = (uint32_t*)d_ws;

    const bool use_keys = ws_size >= (size_t)WS_KEYS_NEED;
    uint32_t* keys = (uint32_t*)((char*)d_ws) + OFF_KEYS;  // only written if use_keys

    const dim3 hgrid(HBLK, NIMG);
    hist0_k<<<hgrid, HTHR, 0, stream>>>(dp, dg, vmask, keys, ws, use_keys ? 1 : 0);
    select_k<21, 8><<<NIMG, 256, 0, stream>>>(ws, intr, posegt, posepred);
    if (use_keys) {
        histN_k<true><<<hgrid, HTHR, 0, stream>>>(dp, dg, vmask, keys, ws, 1);
        select_k<10, 8><<<NIMG, 256, 0, stream>>>(ws, intr, posegt, posepred);
        histN_k<true><<<hgrid, HTHR, 0, stream>>>(dp, dg, vmask, keys, ws, 2);
        select_k<0, 4><<<NIMG, 256, 0, stream>>>(ws, intr, posegt, posepred);
    } else {
        histN_k<false><<<hgrid, HTHR, 0, stream>>>(dp, dg, vmask, keys, ws, 1);
        select_k<10, 8><<<NIMG, 256, 0, stream>>>(ws, intr, posegt, posepred);
        histN_k<false><<<hgrid, HTHR, 0, stream>>>(dp, dg, vmask, keys, ws, 2);
        select_k<0, 4><<<NIMG, 256, 0, stream>>>(ws, intr, posegt, posepred);
    }

    main_loss<<<dim3(192, NIMG), 256, 0, stream>>>(dp, dg, vmask, pts_pred, intr, posegt, ws);
    finalize_k<<<1, 256, 0, stream>>>(ws, out);
}